// Round 6
// baseline (130.157 us; speedup 1.0000x reference)
//
#include <hip/hip_runtime.h>
#include <hip/hip_bf16.h>
#include <cstdint>

typedef __attribute__((ext_vector_type(4))) float f32x4;
typedef __attribute__((ext_vector_type(8))) short s16x8;
typedef __attribute__((ext_vector_type(4))) unsigned short u16x4;
typedef unsigned short u16;
typedef unsigned int u32;
typedef unsigned long long u64;

__device__ __forceinline__ float b2f(u16 u){ u32 v = ((u32)u)<<16; return __builtin_bit_cast(float, v); }
__device__ __forceinline__ u16 f2b(float f){
  __hip_bfloat16 h = __float2bfloat16(f);     // hw v_cvt path (RNE)
  return __builtin_bit_cast(u16, h);
}

__device__ __forceinline__ void gld16(const void* g, void* l){
  __builtin_amdgcn_global_load_lds((const __attribute__((address_space(1))) void*)g,
                                   (__attribute__((address_space(3))) void*)l, 16, 0, 0);
}

__device__ __forceinline__ f32x4 mfma16(s16x8 a, s16x8 b, f32x4 c){
  return __builtin_amdgcn_mfma_f32_16x16x32_bf16(a, b, c, 0, 0, 0);
}

// workspace element offsets (u16 elements)
#define WS_XB   0u           // [4096][1024] bf16 x
#define WS_WQ   (4u<<20)
#define WS_WK   (5u<<20)
#define WS_WV   (6u<<20)
#define WS_WO   (7u<<20)
#define WS_Q    (8u<<20)     // (B,H,S,HD) bf16, RoPE'd, Q scaled by 0.125*log2(e)
#define WS_K    (12u<<20)    // (B,H,S,HD) bf16, RoPE'd
#define WS_VT   (16u<<20)    // [1024][4096] bf16  (V^T: rows h*64+hd, cols b*2048+s)
#define WS_AO   (20u<<20)    // (B,S,D) bf16 attention output

#define QSCALE 0.18033688f   // 0.125 * log2(e): QK^T result is in log2 domain

// ---------------- convert fp32 -> bf16 (x + 4 weights) ----------------
__global__ __launch_bounds__(256) void k_convert(const float* __restrict__ x,
    const float* __restrict__ wq, const float* __restrict__ wk,
    const float* __restrict__ wv, const float* __restrict__ wo,
    u16* __restrict__ ws){
  u32 idx = blockIdx.x*256u + threadIdx.x;   // f32x4 index; total 2M
  const float* src; u16* dst;
  if (idx < (1u<<20)) { src = x + (u64)idx*4u; dst = ws + WS_XB + (u64)idx*4u; }
  else {
    u32 widx = idx - (1u<<20);
    u32 wsel = widx >> 18;
    u32 off  = (widx & ((1u<<18)-1u)) * 4u;
    const float* sp = (wsel==0u)?wq:(wsel==1u)?wk:(wsel==2u)?wv:wo;
    src = sp + off; dst = ws + WS_WQ + (u64)wsel*(1u<<20) + off;
  }
  f32x4 v = *(const f32x4*)src;
  u16x4 o = { f2b(v[0]), f2b(v[1]), f2b(v[2]), f2b(v[3]) };
  *(u16x4*)dst = o;
}

// ---------------- GEMM: C[i][j] = sum_k A[i][k]*B[j][k] (both row-major, K=1024) -----
// BK=64 (16 K-steps, 32 MFMA per barrier-pair). LDS rows 128B, XOR swizzle (row&7)<<4.
// pass 0: 768 blocks (seg0=Q, seg1=K -> LDS C-tile -> RoPE -> scatter; seg2 = V^T)
// pass 1: 256 blocks: out = AO @ WO^T -> fp32
__global__ __launch_bounds__(256,3) void k_gemm(u16* __restrict__ ws, float* __restrict__ out,
    const float* __restrict__ fc, const float* __restrict__ fs, int pass){
  __shared__ char sm[32768];   // A tile 16KB | B tile 16KB; reused as bf16 C tile (modes 0/1)
  const u32 tid = threadIdx.x;
  const u32 w = tid>>6, l = tid&63u, g = l>>4, li = l&15u;
  const u32 wr = w>>1, wc = w&1u;
  u32 bx = blockIdx.x;

  const u16 *Ap, *Bp; u32 arow0, brow0; int mode;
  if (pass == 0) {
    u32 seg = bx >> 8, b2 = bx & 255u;
    if (seg < 2u) {
      Ap = ws + WS_XB; Bp = ws + (seg ? WS_WK : WS_WQ);
      arow0 = (b2 >> 3) * 128u; brow0 = (b2 & 7u) * 128u; mode = (int)seg;   // 0=Q 1=K
    } else {
      Ap = ws + WS_WV; Bp = ws + WS_XB;
      arow0 = (b2 >> 5) * 128u; brow0 = (b2 & 31u) * 128u; mode = 2;         // V^T
    }
  } else {
    Ap = ws + WS_AO; Bp = ws + WS_WO;
    arow0 = (bx >> 3) * 128u; brow0 = (bx & 7u) * 128u; mode = 3;            // O proj
  }

  f32x4 acc[4][4];
  #pragma unroll
  for (u32 m=0;m<4;++m)
    #pragma unroll
    for (u32 n=0;n<4;++n) acc[m][n] = 0.0f;

  for (u32 t = 0; t < 16u; ++t) {
    const u32 k0 = t*64u;
    #pragma unroll
    for (u32 j = 0; j < 4u; ++j) {
      u32 p = w*4096u + j*1024u + l*16u;     // byte pos in 16KB tile
      u32 row = p >> 7, colb = p & 127u;
      u32 cS = colb ^ ((row & 7u) << 4);
      gld16(Ap + (u64)(arow0 + row)*1024u + k0 + (cS>>1), sm + w*4096u + j*1024u);
      gld16(Bp + (u64)(brow0 + row)*1024u + k0 + (cS>>1), sm + 16384u + w*4096u + j*1024u);
    }
    __syncthreads();
    s16x8 af[2][4], bf[2][4];
    #pragma unroll
    for (u32 kk=0;kk<2u;++kk){
      #pragma unroll
      for (u32 m=0;m<4;++m){
        u32 row = wr*64u + m*16u + li;
        af[kk][m] = *(const s16x8*)(sm + row*128u + ((kk*64u + g*16u) ^ ((row&7u)<<4)));
      }
      #pragma unroll
      for (u32 n=0;n<4;++n){
        u32 row = wc*64u + n*16u + li;
        bf[kk][n] = *(const s16x8*)(sm + 16384u + row*128u + ((kk*64u + g*16u) ^ ((row&7u)<<4)));
      }
    }
    #pragma unroll
    for (u32 kk=0;kk<2u;++kk)
      #pragma unroll
      for (u32 m=0;m<4;++m)
        #pragma unroll
        for (u32 n=0;n<4;++n)
          acc[m][n] = mfma16(af[kk][m], bf[kk][n], acc[m][n]);
    __syncthreads();
  }

  u16* qdst = ws + WS_Q; u16* kdst = ws + WS_K; u16* vtd = ws + WS_VT;
  if (mode <= 1) {
    // stage C tile (128 rows x 128 cols bf16, 256B rows) in LDS, swizzled
    #pragma unroll
    for (u32 m=0;m<4;++m)
      #pragma unroll
      for (u32 n=0;n<4;++n)
        #pragma unroll
        for (u32 q=0;q<4;++q){
          u32 row = wr*64u + m*16u + 4u*g + q;
          u32 colb = (wc*64u + n*16u + li)*2u;
          *(u16*)(sm + row*256u + (colb ^ ((row&7u)<<4))) = f2b(acc[m][n][q]);
        }
    __syncthreads();
    // one thread = one row-half: RoPE pairs adjacent in-register, coalesced tables+stores
    u32 row = tid >> 1, half = tid & 1u;
    u32 r = arow0 + row;
    u32 b = r >> 11, s = r & 2047u;
    u32 h = (brow0 >> 6) + half;
    float qs = (mode==0) ? QSCALE : 1.0f;
    u16* d = ((mode==0) ? qdst : kdst) + (u64)(((b<<4)+h)*2048u + s)*64u;
    #pragma unroll
    for (u32 u0=0; u0<8u; ++u0){
      s16x8 cv = *(const s16x8*)(sm + row*256u + ((half*128u + u0*16u) ^ ((row&7u)<<4)));
      f32x4 cvv = *(const f32x4*)(fc + s*32u + u0*4u);
      f32x4 svv = *(const f32x4*)(fs + s*32u + u0*4u);
      s16x8 o;
      #pragma unroll
      for (u32 i=0;i<4;++i){
        float t0 = b2f((u16)cv[2*i]), t1 = b2f((u16)cv[2*i+1]);
        o[2*i]   = (short)f2b((t0*cvv[i] - t1*svv[i])*qs);
        o[2*i+1] = (short)f2b((t0*svv[i] + t1*cvv[i])*qs);
      }
      *(s16x8*)(d + u0*8u) = o;
    }
  } else {
    #pragma unroll
    for (u32 m=0;m<4;++m){
      u32 r0 = arow0 + wr*64u + m*16u + 4u*g;
      #pragma unroll
      for (u32 n=0;n<4;++n){
        u32 c = brow0 + wc*64u + n*16u + li;
        #pragma unroll
        for (u32 q=0;q<4;++q){
          float v = acc[m][n][q];
          u32 r = r0 + q;
          if (mode == 2) vtd[(u64)r*4096u + c] = f2b(v);
          else           out[(u64)r*1024u + c] = v;
        }
      }
    }
  }
}

// ---------------- Flash attention (causal), 4 waves x 32 q-rows, KVBLK=64 ----------------
// Double-buffered K/V: STAGE(next) issued BEFORE compute, single barrier per tile
// (its vmcnt(0) drain lands after ~600cyc of compute -> prefetch latency hidden).
// Static-shift softmax in log2 domain; row sums via ones-MFMA.
__global__ __launch_bounds__(256) void k_attn(u16* __restrict__ ws){
  __shared__ char sm[51200];  // K dbuf 2x8KB | V dbuf 2x8KB | P per wave 32x144B
  const u32 tid = threadIdx.x;
  const u32 w = tid>>6, l = tid&63u, g = l>>4, li = l&15u;
  u32 bx = blockIdx.x;
  u32 k5 = bx >> 5;
  u32 qt = (k5 < 8u) ? (15u - 2u*k5) : (2u*k5 - 16u);  // balanced-makespan pairing
  u32 bh = bx & 31u;
  u32 b = bh >> 4, h = bh & 15u;
  const u16* Q  = ws + WS_Q + (u64)bh*2048u*64u;
  const u16* Kp = ws + WS_K + (u64)bh*2048u*64u;
  const u16* Vt = ws + WS_VT + (u64)(h*64u)*4096u + b*2048u;
  u16* AO = ws + WS_AO;
  const u32 qw = qt*128u + w*32u;

  s16x8 qa[2][2];
  #pragma unroll
  for (u32 m=0;m<2;++m)
    #pragma unroll
    for (u32 kk=0;kk<2;++kk)
      qa[m][kk] = *(const s16x8*)(Q + (u64)(qw + m*16u + li)*64u + kk*32u + g*8u);

  s16x8 ones;
  #pragma unroll
  for (u32 i=0;i<8;++i) ones[i] = (short)0x3F80;   // bf16 1.0

  f32x4 o[2][4]; f32x4 lsum[2];
  #pragma unroll
  for (u32 m=0;m<2;++m){
    #pragma unroll
    for (u32 n=0;n<4;++n) o[m][n] = 0.0f;
    lsum[m] = 0.0f;
  }

  char* pl = sm + 32768 + w*4608u;   // 32 rows x 144B (64 bf16 cols + pad)
  const u32 nt = qt*2u + 2u;

  // stage K/V tile into buffer cb (byte offset), kv base row kvb
  auto STAGE = [&](u32 cb, u32 kvb){
    #pragma unroll
    for (u32 j=0;j<2u;++j){
      u32 p = (w*2u+j)*1024u + l*16u;
      u32 row = p >> 7, colb = p & 127u;
      u32 cS = colb ^ ((row & 7u) << 4);
      gld16(Kp + (u64)(kvb + row)*64u + (cS>>1), sm + cb + (w*2u+j)*1024u);
      gld16(Vt + (u64)row*4096u + kvb + (cS>>1), sm + 16384u + cb + (w*2u+j)*1024u);
    }
  };

  STAGE(0u, 0u);
  __syncthreads();

  u32 cur = 0u;
  for (u32 t = 0; t < nt; ++t) {
    const u32 kvb = t*64u;
    if (t + 1u < nt) STAGE((cur^1u)*8192u, kvb + 64u);   // issue-early prefetch
    if (kvb <= qw + 31u) {
      const u32 cb = cur*8192u;
      f32x4 sv[2][4];
      #pragma unroll
      for (u32 m=0;m<2;++m)
        #pragma unroll
        for (u32 n=0;n<4;++n) sv[m][n] = 0.0f;
      #pragma unroll
      for (u32 n=0;n<4;++n){
        u32 kvr = n*16u + li;
        #pragma unroll
        for (u32 kk=0;kk<2u;++kk){
          s16x8 kf = *(const s16x8*)(sm + cb + kvr*128u + ((kk*64u + g*16u) ^ ((kvr&7u)<<4)));
          #pragma unroll
          for (u32 m=0;m<2;++m)
            sv[m][n] = mfma16(qa[m][kk], kf, sv[m][n]);
        }
      }
      if (kvb + 63u > qw) {   // causally partial tile for this wave
        #pragma unroll
        for (u32 m=0;m<2;++m)
          #pragma unroll
          for (u32 n=0;n<4;++n)
            #pragma unroll
            for (u32 q=0;q<4;++q){
              u32 qr = qw + m*16u + 4u*g + q;
              u32 kc = kvb + n*16u + li;
              if (kc > qr) sv[m][n][q] = -1e9f;
            }
      }
      // p = exp2(s2) -> bf16 P in LDS
      #pragma unroll
      for (u32 m=0;m<2;++m)
        #pragma unroll
        for (u32 n=0;n<4;++n)
          #pragma unroll
          for (u32 q=0;q<4;++q)
            *(u16*)(pl + (m*16u + 4u*g + q)*144u + (n*16u + li)*2u) = f2b(exp2f(sv[m][n][q]));
      // PV + row-sum (ones-column MFMA)
      #pragma unroll
      for (u32 kk=0;kk<2u;++kk){
        s16x8 pa[2];
        #pragma unroll
        for (u32 m=0;m<2;++m){
          pa[m] = *(const s16x8*)(pl + (m*16u + li)*144u + kk*64u + g*16u);
          lsum[m] = mfma16(pa[m], ones, lsum[m]);
        }
        #pragma unroll
        for (u32 n=0;n<4;++n){
          u32 hr = n*16u + li;
          s16x8 vf = *(const s16x8*)(sm + 16384u + cb + hr*128u + ((kk*64u + g*16u) ^ ((hr&7u)<<4)));
          #pragma unroll
          for (u32 m=0;m<2;++m)
            o[m][n] = mfma16(pa[m], vf, o[m][n]);
        }
      }
    }
    __syncthreads();   // drains prefetch (issued ~600cyc ago) + protects buffer reuse
    cur ^= 1u;
  }

  // epilogue: normalize by MFMA row sums, write (B,S,D) bf16
  #pragma unroll
  for (u32 m=0;m<2;++m)
    #pragma unroll
    for (u32 q=0;q<4;++q){
      float inv = 1.0f / lsum[m][q];
      u32 qr = qw + m*16u + 4u*g + q;
      #pragma unroll
      for (u32 n=0;n<4;++n){
        u32 hd = n*16u + li;
        AO[((u64)(b*2048u + qr))*1024u + h*64u + hd] = f2b(o[m][n][q] * inv);
      }
    }
}

extern "C" void kernel_launch(void* const* d_in, const int* in_sizes, int n_in,
                              void* d_out, int out_size, void* d_ws, size_t ws_size,
                              hipStream_t stream) {
  const float* x  = (const float*)d_in[0];
  const float* fc = (const float*)d_in[1];
  const float* fs = (const float*)d_in[2];
  // d_in[3] = mask (unused; causal mask applied analytically)
  const float* wq = (const float*)d_in[4];
  const float* wk = (const float*)d_in[5];
  const float* wv = (const float*)d_in[6];
  const float* wo = (const float*)d_in[7];
  u16* ws = (u16*)d_ws;
  float* out = (float*)d_out;

  k_convert<<<8192, 256, 0, stream>>>(x, wq, wk, wv, wo, ws);
  k_gemm  <<<768,  256, 0, stream>>>(ws, out, fc, fs, 0);   // Q,K (RoPE fused), V^T
  k_attn  <<<512,  256, 0, stream>>>(ws);                   // causal flash attention
  k_gemm  <<<256,  256, 0, stream>>>(ws, out, fc, fs, 1);   // output projection -> fp32
}

// Round 7
// 108.318 us; speedup vs baseline: 1.2016x; 1.2016x over previous
//
#include <hip/hip_runtime.h>
#include <hip/hip_bf16.h>
#include <cstdint>

typedef __attribute__((ext_vector_type(4))) float f32x4;
typedef __attribute__((ext_vector_type(8))) short s16x8;
typedef __attribute__((ext_vector_type(4))) unsigned short u16x4;
typedef unsigned short u16;
typedef unsigned int u32;
typedef unsigned long long u64;

__device__ __forceinline__ float b2f(u16 u){ u32 v = ((u32)u)<<16; return __builtin_bit_cast(float, v); }
__device__ __forceinline__ u16 f2b(float f){
  __hip_bfloat16 h = __float2bfloat16(f);     // hw v_cvt path (RNE)
  return __builtin_bit_cast(u16, h);
}

__device__ __forceinline__ void gld16(const void* g, void* l){
  __builtin_amdgcn_global_load_lds((const __attribute__((address_space(1))) void*)g,
                                   (__attribute__((address_space(3))) void*)l, 16, 0, 0);
}

__device__ __forceinline__ f32x4 mfma16(s16x8 a, s16x8 b, f32x4 c){
  return __builtin_amdgcn_mfma_f32_16x16x32_bf16(a, b, c, 0, 0, 0);
}

// workspace element offsets (u16 elements)
#define WS_XB   0u           // [4096][1024] bf16 x
#define WS_WQ   (4u<<20)
#define WS_WK   (5u<<20)
#define WS_WV   (6u<<20)
#define WS_WO   (7u<<20)
#define WS_Q    (8u<<20)     // (B,H,S,HD) bf16, RoPE'd, Q scaled by 0.125*log2(e)
#define WS_K    (12u<<20)    // (B,H,S,HD) bf16, RoPE'd
#define WS_VT   (16u<<20)    // [1024][4096] bf16  (V^T: rows h*64+hd, cols b*2048+s)
#define WS_AO   (20u<<20)    // (B,S,D) bf16 attention output

#define QSCALE 0.18033688f   // 0.125 * log2(e): QK^T result is in log2 domain

// ---------------- convert fp32 -> bf16 (x + 4 weights) ----------------
__global__ __launch_bounds__(256) void k_convert(const float* __restrict__ x,
    const float* __restrict__ wq, const float* __restrict__ wk,
    const float* __restrict__ wv, const float* __restrict__ wo,
    u16* __restrict__ ws){
  u32 idx = blockIdx.x*256u + threadIdx.x;   // f32x4 index; total 2M
  const float* src; u16* dst;
  if (idx < (1u<<20)) { src = x + (u64)idx*4u; dst = ws + WS_XB + (u64)idx*4u; }
  else {
    u32 widx = idx - (1u<<20);
    u32 wsel = widx >> 18;
    u32 off  = (widx & ((1u<<18)-1u)) * 4u;
    const float* sp = (wsel==0u)?wq:(wsel==1u)?wk:(wsel==2u)?wv:wo;
    src = sp + off; dst = ws + WS_WQ + (u64)wsel*(1u<<20) + off;
  }
  f32x4 v = *(const f32x4*)src;
  u16x4 o = { f2b(v[0]), f2b(v[1]), f2b(v[2]), f2b(v[3]) };
  *(u16x4*)dst = o;
}

// ---------------- GEMM: C[i][j] = sum_k A[i][k]*B[j][k] (both row-major, K=1024) -----
// BK=64, double-buffered: stage t+1 issued BEFORE compute of stage t, one barrier/step.
// LDS rows 128B, XOR swizzle (row&7)<<4.
// pass 0: 768 blocks (seg0=Q, seg1=K -> LDS C-tile -> RoPE -> scatter; seg2 = V^T)
// pass 1: 256 blocks: out = AO @ WO^T -> fp32
__global__ __launch_bounds__(256,2) void k_gemm(u16* __restrict__ ws, float* __restrict__ out,
    const float* __restrict__ fc, const float* __restrict__ fs, int pass){
  __shared__ char sm[65536];   // 2 stages x {A 16KB | B 16KB}; stage0 reused as C tile
  const u32 tid = threadIdx.x;
  const u32 w = tid>>6, l = tid&63u, g = l>>4, li = l&15u;
  const u32 wr = w>>1, wc = w&1u;
  u32 bx = blockIdx.x;

  const u16 *Ap, *Bp; u32 arow0, brow0; int mode;
  if (pass == 0) {
    u32 seg = bx >> 8, b2 = bx & 255u;
    if (seg < 2u) {
      Ap = ws + WS_XB; Bp = ws + (seg ? WS_WK : WS_WQ);
      arow0 = (b2 >> 3) * 128u; brow0 = (b2 & 7u) * 128u; mode = (int)seg;   // 0=Q 1=K
    } else {
      Ap = ws + WS_WV; Bp = ws + WS_XB;
      arow0 = (b2 >> 5) * 128u; brow0 = (b2 & 31u) * 128u; mode = 2;         // V^T
    }
  } else {
    Ap = ws + WS_AO; Bp = ws + WS_WO;
    arow0 = (bx >> 3) * 128u; brow0 = (bx & 7u) * 128u; mode = 3;            // O proj
  }

  f32x4 acc[4][4];
  #pragma unroll
  for (u32 m=0;m<4;++m)
    #pragma unroll
    for (u32 n=0;n<4;++n) acc[m][n] = 0.0f;

  // stage K-step t into stage buffer s
  auto STAGE_G = [&](u32 s, u32 t){
    const u32 k0 = t*64u;
    #pragma unroll
    for (u32 j = 0; j < 4u; ++j) {
      u32 p = w*4096u + j*1024u + l*16u;     // byte pos in 16KB tile
      u32 row = p >> 7, colb = p & 127u;
      u32 cS = colb ^ ((row & 7u) << 4);
      gld16(Ap + (u64)(arow0 + row)*1024u + k0 + (cS>>1), sm + s*32768u + w*4096u + j*1024u);
      gld16(Bp + (u64)(brow0 + row)*1024u + k0 + (cS>>1), sm + s*32768u + 16384u + w*4096u + j*1024u);
    }
  };

  STAGE_G(0u, 0u);
  __syncthreads();

  u32 cur = 0u;
  for (u32 t = 0; t < 16u; ++t) {
    if (t + 1u < 16u) STAGE_G(cur^1u, t+1u);   // issue-early prefetch
    const u32 cb = cur*32768u;
    s16x8 af[2][4], bf[2][4];
    #pragma unroll
    for (u32 kk=0;kk<2u;++kk){
      #pragma unroll
      for (u32 m=0;m<4;++m){
        u32 row = wr*64u + m*16u + li;
        af[kk][m] = *(const s16x8*)(sm + cb + row*128u + ((kk*64u + g*16u) ^ ((row&7u)<<4)));
      }
      #pragma unroll
      for (u32 n=0;n<4;++n){
        u32 row = wc*64u + n*16u + li;
        bf[kk][n] = *(const s16x8*)(sm + cb + 16384u + row*128u + ((kk*64u + g*16u) ^ ((row&7u)<<4)));
      }
    }
    #pragma unroll
    for (u32 kk=0;kk<2u;++kk)
      #pragma unroll
      for (u32 m=0;m<4;++m)
        #pragma unroll
        for (u32 n=0;n<4;++n)
          acc[m][n] = mfma16(af[kk][m], bf[kk][n], acc[m][n]);
    __syncthreads();   // drains prefetch (issued before compute) + protects reuse
    cur ^= 1u;
  }

  u16* qdst = ws + WS_Q; u16* kdst = ws + WS_K; u16* vtd = ws + WS_VT;
  if (mode <= 1) {
    // stage C tile (128 rows x 128 cols bf16, 256B rows) in LDS stage0, swizzled
    #pragma unroll
    for (u32 m=0;m<4;++m)
      #pragma unroll
      for (u32 n=0;n<4;++n)
        #pragma unroll
        for (u32 q=0;q<4;++q){
          u32 row = wr*64u + m*16u + 4u*g + q;
          u32 colb = (wc*64u + n*16u + li)*2u;
          *(u16*)(sm + row*256u + (colb ^ ((row&7u)<<4))) = f2b(acc[m][n][q]);
        }
    __syncthreads();
    // one thread = one row-half: RoPE pairs adjacent in-register, coalesced tables+stores
    u32 row = tid >> 1, half = tid & 1u;
    u32 r = arow0 + row;
    u32 b = r >> 11, s = r & 2047u;
    u32 h = (brow0 >> 6) + half;
    float qs = (mode==0) ? QSCALE : 1.0f;
    u16* d = ((mode==0) ? qdst : kdst) + (u64)(((b<<4)+h)*2048u + s)*64u;
    #pragma unroll
    for (u32 u0=0; u0<8u; ++u0){
      s16x8 cv = *(const s16x8*)(sm + row*256u + ((half*128u + u0*16u) ^ ((row&7u)<<4)));
      f32x4 cvv = *(const f32x4*)(fc + s*32u + u0*4u);
      f32x4 svv = *(const f32x4*)(fs + s*32u + u0*4u);
      s16x8 o;
      #pragma unroll
      for (u32 i=0;i<4;++i){
        float t0 = b2f((u16)cv[2*i]), t1 = b2f((u16)cv[2*i+1]);
        o[2*i]   = (short)f2b((t0*cvv[i] - t1*svv[i])*qs);
        o[2*i+1] = (short)f2b((t0*svv[i] + t1*cvv[i])*qs);
      }
      *(s16x8*)(d + u0*8u) = o;
    }
  } else {
    #pragma unroll
    for (u32 m=0;m<4;++m){
      u32 r0 = arow0 + wr*64u + m*16u + 4u*g;
      #pragma unroll
      for (u32 n=0;n<4;++n){
        u32 c = brow0 + wc*64u + n*16u + li;
        #pragma unroll
        for (u32 q=0;q<4;++q){
          float v = acc[m][n][q];
          u32 r = r0 + q;
          if (mode == 2) vtd[(u64)r*4096u + c] = f2b(v);
          else           out[(u64)r*1024u + c] = v;
        }
      }
    }
  }
}

// ---------------- Flash attention (causal), 4 waves x 16 q-rows, KVBLK=64 ----------------
// R5 geometry (grid 1024, LPT heavy-first, 41KB LDS -> 3 blocks/CU) + double-buffered
// K/V with issue-early staging: prefetch for tile t+1 issued before compute of tile t,
// single barrier per tile. Static-shift softmax in log2 domain; row sums via ones-MFMA.
__global__ __launch_bounds__(256) void k_attn(u16* __restrict__ ws){
  __shared__ char sm[41984];  // 2 stages x {K 8KB | V 8KB} | P 4 x 2304B
  const u32 tid = threadIdx.x;
  const u32 w = tid>>6, l = tid&63u, g = l>>4, li = l&15u;
  u32 bx = blockIdx.x;
  u32 qt = 31u - (bx >> 5);     // heavy q-tiles dispatched first (LPT)
  u32 bh = bx & 31u;
  u32 b = bh >> 4, h = bh & 15u;
  const u16* Q  = ws + WS_Q + (u64)bh*2048u*64u;
  const u16* Kp = ws + WS_K + (u64)bh*2048u*64u;
  const u16* Vt = ws + WS_VT + (u64)(h*64u)*4096u + b*2048u;
  u16* AO = ws + WS_AO;
  const u32 qw = qt*64u + w*16u;

  s16x8 qa[2];
  #pragma unroll
  for (u32 kk=0;kk<2;++kk)
    qa[kk] = *(const s16x8*)(Q + (u64)(qw + li)*64u + kk*32u + g*8u);

  s16x8 ones;
  #pragma unroll
  for (u32 i=0;i<8;++i) ones[i] = (short)0x3F80;   // bf16 1.0

  f32x4 o[4]; f32x4 lsum;
  #pragma unroll
  for (u32 n=0;n<4;++n) o[n] = 0.0f;
  lsum = 0.0f;

  char* pl = sm + 32768 + w*2304u;   // 16 rows x 144B (64 bf16 cols + pad)
  const u32 nt = qt + 1u;

  // stage K/V tile (64 rows) into stage s from kv base row kvb
  auto STAGE = [&](u32 s, u32 kvb){
    #pragma unroll
    for (u32 j=0;j<2u;++j){
      u32 p = (w*2u+j)*1024u + l*16u;
      u32 row = p >> 7, colb = p & 127u;
      u32 cS = colb ^ ((row & 7u) << 4);
      gld16(Kp + (u64)(kvb + row)*64u + (cS>>1), sm + s*16384u + (w*2u+j)*1024u);
      gld16(Vt + (u64)row*4096u + kvb + (cS>>1), sm + s*16384u + 8192u + (w*2u+j)*1024u);
    }
  };

  STAGE(0u, 0u);
  __syncthreads();

  u32 cur = 0u;
  for (u32 t = 0; t < nt; ++t) {
    const u32 kvb = t*64u;
    if (t + 1u < nt) STAGE(cur^1u, kvb + 64u);   // issue-early prefetch
    const u32 cb = cur*16384u;

    f32x4 sv[4];
    #pragma unroll
    for (u32 n=0;n<4;++n) sv[n] = 0.0f;
    #pragma unroll
    for (u32 n=0;n<4;++n){
      u32 kvr = n*16u + li;
      #pragma unroll
      for (u32 kk=0;kk<2u;++kk){
        s16x8 kf = *(const s16x8*)(sm + cb + kvr*128u + ((kk*64u + g*16u) ^ ((kvr&7u)<<4)));
        sv[n] = mfma16(qa[kk], kf, sv[n]);
      }
    }
    if (t == nt - 1u) {   // only the last tile is causally partial
      #pragma unroll
      for (u32 n=0;n<4;++n)
        #pragma unroll
        for (u32 q=0;q<4;++q){
          u32 qr = qw + 4u*g + q;
          u32 kc = kvb + n*16u + li;
          if (kc > qr) sv[n][q] = -1e9f;
        }
    }
    // p = exp2(s2) -> bf16 P in LDS (native cvt)
    #pragma unroll
    for (u32 n=0;n<4;++n)
      #pragma unroll
      for (u32 q=0;q<4;++q)
        *(u16*)(pl + (4u*g + q)*144u + (n*16u + li)*2u) = f2b(exp2f(sv[n][q]));
    // PV + row-sum (ones-column MFMA)
    #pragma unroll
    for (u32 kk=0;kk<2u;++kk){
      s16x8 pa = *(const s16x8*)(pl + li*144u + kk*64u + g*16u);
      lsum = mfma16(pa, ones, lsum);
      #pragma unroll
      for (u32 n=0;n<4;++n){
        u32 hr = n*16u + li;
        s16x8 vf = *(const s16x8*)(sm + cb + 8192u + hr*128u + ((kk*64u + g*16u) ^ ((hr&7u)<<4)));
        o[n] = mfma16(pa, vf, o[n]);
      }
    }
    __syncthreads();   // drains prefetch (issued before compute) + protects buffer reuse
    cur ^= 1u;
  }

  // epilogue: normalize by MFMA row sums, write (B,S,D) bf16
  #pragma unroll
  for (u32 q=0;q<4;++q){
    float inv = 1.0f / lsum[q];
    u32 qr = qw + 4u*g + q;
    #pragma unroll
    for (u32 n=0;n<4;++n){
      u32 hd = n*16u + li;
      AO[((u64)(b*2048u + qr))*1024u + h*64u + hd] = f2b(o[n][q] * inv);
    }
  }
}

extern "C" void kernel_launch(void* const* d_in, const int* in_sizes, int n_in,
                              void* d_out, int out_size, void* d_ws, size_t ws_size,
                              hipStream_t stream) {
  const float* x  = (const float*)d_in[0];
  const float* fc = (const float*)d_in[1];
  const float* fs = (const float*)d_in[2];
  // d_in[3] = mask (unused; causal mask applied analytically)
  const float* wq = (const float*)d_in[4];
  const float* wk = (const float*)d_in[5];
  const float* wv = (const float*)d_in[6];
  const float* wo = (const float*)d_in[7];
  u16* ws = (u16*)d_ws;
  float* out = (float*)d_out;

  k_convert<<<8192, 256, 0, stream>>>(x, wq, wk, wv, wo, ws);
  k_gemm  <<<768,  256, 0, stream>>>(ws, out, fc, fs, 0);   // Q,K (RoPE fused), V^T
  k_attn  <<<1024, 256, 0, stream>>>(ws);                   // causal flash attention
  k_gemm  <<<256,  256, 0, stream>>>(ws, out, fc, fs, 1);   // output projection -> fp32
}